// Round 3
// 992.207 us; speedup vs baseline: 1.3342x; 1.3342x over previous
//
#include <hip/hip_runtime.h>
#include <math.h>

#define RADIUS 3
#define T_STEPS 2
#define TASKS 4
#define IN_ATOM 39
#define IN_BOND 10
#define FD 256
#define Bm 128
#define Lm 128
#define Dm 6
#define NBONDSm 256
#define NEGV -9e8f
#define NROWS (Bm*Lm)   /* 16384 */
#define WPLANE 196608   /* 768*256 elements per weight plane */

typedef __attribute__((ext_vector_type(8))) short bf16x8;
typedef __attribute__((ext_vector_type(4))) float f32x4;

__device__ __forceinline__ float lrelu(float x){ return x > 0.f ? x : 0.01f*x; }
__device__ __forceinline__ float eluf(float x){ return x > 0.f ? x : expm1f(x); }
__device__ __forceinline__ float sigm(float x){ return 1.f/(1.f+expf(-x)); }
__device__ __forceinline__ float dot4(float4 a, float4 b){
  return a.x*b.x + a.y*b.y + a.z*b.z + a.w*b.w;
}
__device__ __forceinline__ float4 lrelu4(float4 v){
  return make_float4(lrelu(v.x),lrelu(v.y),lrelu(v.z),lrelu(v.w));
}
__device__ __forceinline__ float wred(float v){
  #pragma unroll
  for(int o=32;o>0;o>>=1) v += __shfl_xor(v,o,64);
  return v;
}
__device__ __forceinline__ float bsum512(float v, float* red){
  #pragma unroll
  for(int o=32;o>0;o>>=1) v += __shfl_xor(v,o,64);
  __syncthreads();
  if((threadIdx.x&63)==0) red[threadIdx.x>>6]=v;
  __syncthreads();
  float s=0.f;
  #pragma unroll
  for(int i=0;i<8;i++) s+=red[i];
  return s;
}
__device__ __forceinline__ float bmax512(float v, float* red){
  #pragma unroll
  for(int o=32;o>0;o>>=1) v = fmaxf(v,__shfl_xor(v,o,64));
  __syncthreads();
  if((threadIdx.x&63)==0) red[threadIdx.x>>6]=v;
  __syncthreads();
  float s=-1e30f;
  #pragma unroll
  for(int i=0;i<8;i++) s=fmaxf(s,red[i]);
  return s;
}

// fp32 -> bf16 round-to-nearest-even
__device__ __forceinline__ ushort f2bf(float x){
  union { float f; unsigned u; } v; v.f = x;
  unsigned u = v.u;
  unsigned r = (u + 0x7fffu + ((u >> 16) & 1u)) >> 16;
  return (ushort)r;
}
__device__ __forceinline__ float b2f(ushort u){ return __uint_as_float(((unsigned)u)<<16); }

// pack W[n][k] (K=256) -> WP[k/4][N][4]: float4 at (kg*N + n) holds W[n][4kg..4kg+3]
__global__ void k_pack4(const float* __restrict__ W, float* __restrict__ WP, int N){
  int mat = blockIdx.y;
  int idx = blockIdx.x*256 + threadIdx.x;
  if(idx < N*256){
    int n = idx >> 8, k = idx & 255;
    WP[(size_t)mat*N*256 + (size_t)(k>>2)*N*4 + n*4 + (k&3)] = W[(size_t)mat*N*256 + idx];
  }
}

// Dekker 3-way bf16 split + MFMA B-fragment pack.
// Input W [3 radii][768][256] fp32. Output per radius: 3 planes (hi,mid,lo), each
// frag-packed: frag f = nf*8+ks (nf=row/16 over 768, ks=k/32); within frag lane l,
// elem j = W[nf*16+(l&15)][ks*32+(l>>4)*8+j]. Plane stride WPLANE elements.
__global__ __launch_bounds__(256) void k_pack3(
  const float* __restrict__ W, ushort* __restrict__ WP){
  const float* Wm  = W  + (size_t)blockIdx.y*WPLANE;
  ushort*      WPm = WP + (size_t)blockIdx.y*3*WPLANE;
  int id = blockIdx.x*256 + threadIdx.x;   // 0..24575
  int f  = id >> 6;                        // 0..383
  int l  = id & 63;
  int nf = f >> 3;
  int ks = f & 7;
  int n  = nf*16 + (l & 15);
  int k  = ks*32 + (l >> 4)*8;
  const float* src = Wm + (size_t)n*256 + k;
  size_t d0 = ((size_t)f*64 + l)*8;
  #pragma unroll
  for(int j=0;j<8;j++){
    float x = src[j];
    ushort a = f2bf(x); float r1 = x - b2f(a);
    ushort b = f2bf(r1); float r2 = r1 - b2f(b);
    ushort c = f2bf(r2);
    WPm[d0+j] = a; WPm[WPLANE + d0+j] = b; WPm[2*WPLANE + d0+j] = c;
  }
}

// atom_feature = lrelu(atom_list @ atom_fc_w.T + b); atom_proj = atom_list @ nfc_w[:, :39].T
__global__ __launch_bounds__(256) void k_atomfc(
  const float* __restrict__ atom_list, const float* __restrict__ afc_w,
  const float* __restrict__ afc_b, const float* __restrict__ nfc_w,
  float* __restrict__ atom_feature, float* __restrict__ atom_proj){
  __shared__ float Al[16][IN_ATOM];
  int m0 = blockIdx.x*16, t = threadIdx.x;
  for(int i=t;i<16*IN_ATOM;i+=256)
    Al[i/IN_ATOM][i%IN_ATOM] = atom_list[(size_t)(m0 + i/IN_ATOM)*IN_ATOM + i%IN_ATOM];
  __syncthreads();
  float accA[16], accP[16];
  #pragma unroll
  for(int m=0;m<16;m++){accA[m]=0.f;accP[m]=0.f;}
  for(int k=0;k<IN_ATOM;k++){
    float wa = afc_w[t*IN_ATOM+k];
    float wn = nfc_w[t*(IN_ATOM+IN_BOND)+k];
    #pragma unroll
    for(int m=0;m<16;m++){ float a=Al[m][k]; accA[m]+=a*wa; accP[m]+=a*wn; }
  }
  float bb = afc_b[t];
  #pragma unroll
  for(int m=0;m<16;m++){
    atom_feature[(size_t)(m0+m)*FD+t] = lrelu(accA[m]+bb);
    atom_proj[(size_t)(m0+m)*FD+t]    = accP[m];
  }
}

// bond_proj = bond_list @ nfc_w[:, 39:49].T + nfc_b
__global__ __launch_bounds__(256) void k_bondproj(
  const float* __restrict__ bond_list, const float* __restrict__ nfc_w,
  const float* __restrict__ nfc_b, float* __restrict__ bond_proj){
  __shared__ float Bl[16][IN_BOND];
  int m0 = blockIdx.x*16, t=threadIdx.x;
  for(int i=t;i<16*IN_BOND;i+=256)
    Bl[i/IN_BOND][i%IN_BOND] = bond_list[(size_t)(m0+i/IN_BOND)*IN_BOND + i%IN_BOND];
  __syncthreads();
  float acc[16];
  #pragma unroll
  for(int m=0;m<16;m++) acc[m]=0.f;
  for(int k=0;k<IN_BOND;k++){
    float wn = nfc_w[t*(IN_ATOM+IN_BOND)+IN_ATOM+k];
    #pragma unroll
    for(int m=0;m<16;m++) acc[m]+=Bl[m][k]*wn;
  }
  float bb=nfc_b[t];
  #pragma unroll
  for(int m=0;m<16;m++) bond_proj[(size_t)(m0+m)*FD+t]=acc[m]+bb;
}

// radius-0 attention, wave-per-row (4 rows/block). lane owns features lane*4..lane*4+3
__global__ __launch_bounds__(256) void k_attn0(
  const float* __restrict__ AF, const float* __restrict__ APj,
  const float* __restrict__ BP, const int* __restrict__ adeg,
  const int* __restrict__ bdeg, const float* __restrict__ align_w,
  const float* __restrict__ align_b, float* __restrict__ cpre, float* __restrict__ wsum){
  int wid = threadIdx.x>>6, lane = threadIdx.x&63;
  int row = blockIdx.x*4 + wid; int b = row >> 7;
  float4 af = *(const float4*)&AF[(size_t)row*FD + lane*4];
  float4 w1 = *(const float4*)&align_w[lane*4];
  float4 w2 = *(const float4*)&align_w[FD + lane*4];
  float s_self = wred(dot4(af,w1));
  int ia[Dm]; float4 nbr[Dm]; float s_n[Dm];
  #pragma unroll
  for(int d=0;d<Dm;d++){
    ia[d] = adeg[row*Dm+d];
    int ib = bdeg[row*Dm+d];
    float4 ap = *(const float4*)&APj[(size_t)(b*Lm+ia[d])*FD + lane*4];
    float4 bp = *(const float4*)&BP[(size_t)(b*NBONDSm+ib)*FD + lane*4];
    float4 nf = lrelu4(make_float4(ap.x+bp.x,ap.y+bp.y,ap.z+bp.z,ap.w+bp.w));
    nbr[d]=nf;
    s_n[d] = wred(dot4(nf,w2));
  }
  float ab = align_b[0];
  float mx=-1e30f; float sc[Dm];
  #pragma unroll
  for(int d=0;d<Dm;d++){
    sc[d]=lrelu(s_self+s_n[d]+ab) + (ia[d]==Lm-1 ? NEGV : 0.f);
    mx = fmaxf(mx, sc[d]);
  }
  float se=0.f, ex[Dm];
  #pragma unroll
  for(int d=0;d<Dm;d++){ ex[d]=expf(sc[d]-mx); se+=ex[d]; }
  float inv=1.f/se, ws=0.f;
  float4 cp = make_float4(0,0,0,0);
  #pragma unroll
  for(int d=0;d<Dm;d++){
    float wd = ex[d]*inv * (ia[d]==Lm-1?0.f:1.f);
    ws+=wd;
    cp.x+=wd*nbr[d].x; cp.y+=wd*nbr[d].y; cp.z+=wd*nbr[d].z; cp.w+=wd*nbr[d].w;
  }
  *(float4*)&cpre[(size_t)row*FD + lane*4] = cp;
  if(lane==0) wsum[row]=ws;
}

// per-row dots with align_w[r], wave-per-row
__global__ __launch_bounds__(256) void k_dots(
  const float* __restrict__ act, const float* __restrict__ w512,
  float* __restrict__ sself, float* __restrict__ snbr){
  int wid=threadIdx.x>>6, lane=threadIdx.x&63;
  int row=blockIdx.x*4+wid;
  float4 aq = *(const float4*)&act[(size_t)row*FD + lane*4];
  float4 w1 = *(const float4*)&w512[lane*4];
  float4 w2 = *(const float4*)&w512[FD + lane*4];
  float s1 = wred(dot4(aq,w1));
  float s2 = wred(dot4(aq,w2));
  if(lane==0){ sself[row]=s1; snbr[row]=s2; }
}

// radius>=1 attention, wave-per-row
__global__ __launch_bounds__(256) void k_attnr(
  const float* __restrict__ activated, const float* __restrict__ sself,
  const float* __restrict__ snbr, const int* __restrict__ adeg,
  const float* __restrict__ align_b, float* __restrict__ cpre, float* __restrict__ wsum){
  int wid=threadIdx.x>>6, lane=threadIdx.x&63;
  int row=blockIdx.x*4+wid; int b=row>>7;
  float ss = sself[row]; float ab=align_b[0];
  int ia[Dm]; float sc[Dm]; float mx=-1e30f;
  #pragma unroll
  for(int d=0;d<Dm;d++){
    ia[d]=adeg[row*Dm+d];
    sc[d]=lrelu(ss+snbr[b*Lm+ia[d]]+ab)+(ia[d]==Lm-1?NEGV:0.f);
    mx=fmaxf(mx,sc[d]);
  }
  float se=0.f, ex[Dm];
  #pragma unroll
  for(int d=0;d<Dm;d++){ ex[d]=expf(sc[d]-mx); se+=ex[d]; }
  float inv=1.f/se, ws=0.f, wd[Dm];
  #pragma unroll
  for(int d=0;d<Dm;d++){ wd[d]=ex[d]*inv*(ia[d]==Lm-1?0.f:1.f); ws+=wd[d]; }
  float4 cp = make_float4(0,0,0,0);
  #pragma unroll
  for(int d=0;d<Dm;d++){
    float4 av = *(const float4*)&activated[(size_t)(b*Lm+ia[d])*FD + lane*4];
    cp.x+=wd[d]*av.x; cp.y+=wd[d]*av.y; cp.z+=wd[d]*av.z; cp.w+=wd[d]*av.w;
  }
  *(float4*)&cpre[(size_t)row*FD + lane*4] = cp;
  if(lane==0) wsum[row]=ws;
}

// C[M,256] = epi( A[M,256] @ W.T ), W packed [k/4][256][4]. 32 rows/block, 2 cols/thread.
// epi: 2 = elu(acc + wsum[row]*bias), 3 = acc + bias
__global__ __launch_bounds__(256) void k_gemm256(
  const float* __restrict__ A, const float* __restrict__ WP,
  const float* __restrict__ bias, const float* __restrict__ wsum,
  float* __restrict__ C, int epi){
  __shared__ __align__(16) float SA[32][FD];
  int m0=blockIdx.x*32;
  int tc = threadIdx.x & 127;      // column pair: tc, tc+128
  int rg = threadIdx.x >> 7;       // row group of 16
  {
    const float4* A4 = (const float4*)(A + (size_t)m0*FD);
    float4* S4 = (float4*)&SA[0][0];
    for(int i=threadIdx.x;i<32*FD/4;i+=256) S4[i]=A4[i];
  }
  __syncthreads();
  float acc[16][2];
  #pragma unroll
  for(int m=0;m<16;m++){acc[m][0]=0.f;acc[m][1]=0.f;}
  const float4* W4 = (const float4*)WP;
  for(int kg=0;kg<FD/4;kg++){
    float4 b0 = W4[kg*FD + tc];
    float4 b1 = W4[kg*FD + tc+128];
    #pragma unroll
    for(int m=0;m<16;m++){
      float4 aq = *(const float4*)&SA[rg*16+m][kg*4];
      acc[m][0] += dot4(aq,b0);
      acc[m][1] += dot4(aq,b1);
    }
  }
  float bb0 = bias[tc], bb1 = bias[tc+128];
  #pragma unroll
  for(int m=0;m<16;m++){
    int row = m0 + rg*16 + m;
    float v0=acc[m][0], v1=acc[m][1];
    if(epi==2){ float w=wsum[row]; v0=eluf(v0+w*bb0); v1=eluf(v1+w*bb1); }
    else      { v0+=bb0; v1+=bb1; }
    C[(size_t)row*FD+tc]=v0;
    C[(size_t)row*FD+tc+128]=v1;
  }
}

// bf16x3 (Dekker-split) MFMA GRU, ~fp32 precision. 16 rows/block, 4 waves;
// wave w owns within-gate cols [64w,64w+64) of all 6 gate matrices.
// W pre-split into 3 frag-packed bf16 planes (hi/mid/lo); A split on the fly.
// 6 MFMA terms per logical product (i+j<=2) -> rel err ~2^-27 per product.
// Runtime D-vs-D^T calibration vs fp32 recompute (wave 0) retained.
__global__ __launch_bounds__(256) void k_gru_mfma(
  const float* __restrict__ X, const float* Hprev,
  const ushort* __restrict__ WI3, const ushort* __restrict__ WH3,
  const float* __restrict__ Wfp,   // fp32 Wih (this radius), for calibration
  const float* __restrict__ bih, const float* __restrict__ bhh,
  float* Hout, float* __restrict__ Act){
  __shared__ int sflag;
  int lane = threadIdx.x & 63;
  int wv   = threadIdx.x >> 6;
  int rl = lane & 15, rg = lane >> 4;
  int mrow0 = blockIdx.x*16;
  int nf0 = wv*4;

  f32x4 accI[3][4], accH[3][4];
  f32x4 zero = {0.f,0.f,0.f,0.f};
  #pragma unroll
  for(int g=0;g<3;g++)
    #pragma unroll
    for(int c=0;c<4;c++){ accI[g][c]=zero; accH[g][c]=zero; }

  const bf16x8* BI = (const bf16x8*)WI3;   // plane stride in bf16x8 units: WPLANE/8
  const bf16x8* BH = (const bf16x8*)WH3;
  const int PS = WPLANE/8;                 // 24576

  for(int ks=0;ks<8;ks++){
    const float* xp = X     + (size_t)(mrow0+rl)*FD + ks*32 + rg*8;
    const float* hq = Hprev + (size_t)(mrow0+rl)*FD + ks*32 + rg*8;
    bf16x8 x0,x1,x2,h0,h1,h2;
    #pragma unroll
    for(int j=0;j<8;j++){
      float v = xp[j];
      ushort a = f2bf(v); float r1 = v - b2f(a);
      ushort b = f2bf(r1); float r2 = r1 - b2f(b);
      x0[j]=(short)a; x1[j]=(short)b; x2[j]=(short)f2bf(r2);
      float w = hq[j];
      ushort d = f2bf(w); float s1 = w - b2f(d);
      ushort e = f2bf(s1); float s2 = s1 - b2f(e);
      h0[j]=(short)d; h1[j]=(short)e; h2[j]=(short)f2bf(s2);
    }
    #pragma unroll
    for(int c=0;c<4;c++){
      #pragma unroll
      for(int g=0;g<3;g++){
        size_t fb = ((size_t)((g*16 + nf0 + c)*8 + ks))*64 + lane;
        bf16x8 bi0 = BI[fb], bi1 = BI[fb+PS], bi2 = BI[fb+2*PS];
        bf16x8 bh0 = BH[fb], bh1 = BH[fb+PS], bh2 = BH[fb+2*PS];
        f32x4 aI = accI[g][c], aH = accH[g][c];
        aI = __builtin_amdgcn_mfma_f32_16x16x32_bf16(x0, bi0, aI, 0,0,0);
        aI = __builtin_amdgcn_mfma_f32_16x16x32_bf16(x1, bi0, aI, 0,0,0);
        aI = __builtin_amdgcn_mfma_f32_16x16x32_bf16(x0, bi1, aI, 0,0,0);
        aI = __builtin_amdgcn_mfma_f32_16x16x32_bf16(x2, bi0, aI, 0,0,0);
        aI = __builtin_amdgcn_mfma_f32_16x16x32_bf16(x1, bi1, aI, 0,0,0);
        aI = __builtin_amdgcn_mfma_f32_16x16x32_bf16(x0, bi2, aI, 0,0,0);
        aH = __builtin_amdgcn_mfma_f32_16x16x32_bf16(h0, bh0, aH, 0,0,0);
        aH = __builtin_amdgcn_mfma_f32_16x16x32_bf16(h1, bh0, aH, 0,0,0);
        aH = __builtin_amdgcn_mfma_f32_16x16x32_bf16(h0, bh1, aH, 0,0,0);
        aH = __builtin_amdgcn_mfma_f32_16x16x32_bf16(h2, bh0, aH, 0,0,0);
        aH = __builtin_amdgcn_mfma_f32_16x16x32_bf16(h1, bh1, aH, 0,0,0);
        aH = __builtin_amdgcn_mfma_f32_16x16x32_bf16(h0, bh2, aH, 0,0,0);
        accI[g][c]=aI; accH[g][c]=aH;
      }
    }
  }

  // ---- calibration (wave 0): acc is ~fp32-exact now; compare vs fp32 dots ----
  if(wv==0){
    int kk = lane*4;
    float eA=0.f, eB=0.f;
    #pragma unroll
    for(int r=1;r<4;r++){
      float pA=0.f, pB=0.f;
      #pragma unroll
      for(int j=0;j<4;j++){
        pA += X[(size_t)(mrow0+r)*FD + kk+j] * Wfp[kk+j];                 // D[r][0]
        pB += X[(size_t)(mrow0  )*FD + kk+j] * Wfp[(size_t)r*256 + kk+j]; // D[0][r]
      }
      pA = wred(pA); pB = wred(pB);
      float v = accI[0][0][r];
      if(lane==0){ eA += fabsf(v-pA); eB += fabsf(v-pB); }
    }
    if(lane==0) sflag = (eA<=eB) ? 1 : 0;
  }
  __syncthreads();   // publishes sflag AND fences all Hprev reads before in-place writes
  const int fA = sflag;

  #pragma unroll
  for(int c=0;c<4;c++){
    #pragma unroll
    for(int i=0;i<4;i++){
      int row = mrow0 + (fA ? rg*4+i : rl);
      int col = (nf0+c)*16 + (fA ? rl : rg*4+i);
      float br=bih[col],      bz=bih[FD+col],      bn=bih[2*FD+col];
      float cr=bhh[col],      cz=bhh[FD+col],      cn=bhh[2*FD+col];
      float hp = Hprev[(size_t)row*FD + col];
      float r = sigm(accI[0][c][i] + br + accH[0][c][i] + cr);
      float z = sigm(accI[1][c][i] + bz + accH[1][c][i] + cz);
      float n = tanhf(accI[2][c][i] + bn + r*(accH[2][c][i] + cn));
      float hn = (1.f-z)*n + z*hp;
      Hout[(size_t)row*FD+col] = hn;
      Act[(size_t)row*FD+col]  = fmaxf(hn, 0.f);
    }
  }
}

// per-task dots of activated with mol_align_w[i][0][256:512], wave-per-row
__global__ __launch_bounds__(256) void k_sact2(
  const float* __restrict__ act, const float* __restrict__ mol_align_w,
  float* __restrict__ sact2){
  int wid=threadIdx.x>>6, lane=threadIdx.x&63;
  int row=blockIdx.x*4+wid;
  float4 aq = *(const float4*)&act[(size_t)row*FD + lane*4];
  #pragma unroll
  for(int i=0;i<TASKS;i++){
    float4 wq = *(const float4*)&mol_align_w[i*2*FD + FD + lane*4];
    float s = wred(dot4(aq,wq));
    if(lane==0) sact2[(size_t)i*NROWS+row]=s;
  }
}

// fused mol phase: one block per molecule, 512 threads, all TASKS x T_STEPS inside.
__global__ __launch_bounds__(512) void k_molphase(
  const float* __restrict__ ACT, const float* __restrict__ amask,
  const float* __restrict__ sact2, const float* __restrict__ mol_align_w,
  const float* __restrict__ mol_align_b, const float* __restrict__ act_t,
  const float* __restrict__ WihP, const float* __restrict__ WhhP,
  const float* __restrict__ bih, const float* __restrict__ bhh,
  float* __restrict__ out){
  __shared__ __align__(16) float HS[FD];
  __shared__ __align__(16) float XS[FD];
  __shared__ float ACTM[FD];
  __shared__ float GH[3*FD];
  __shared__ float WL[Lm];
  __shared__ float red[8];
  int b = blockIdx.x;
  int t = threadIdx.x;        // 0..511
  int tg = t & 255;
  // mol_feature = sum_l ACT*mask
  if(t<FD){
    float s=0.f;
    for(int l=0;l<Lm;l++) s += ACT[(size_t)(b*Lm+l)*FD+t]*amask[b*Lm+l];
    HS[t]=s; ACTM[t]=fmaxf(s,0.f);
  }
  __syncthreads();
  const float4* WI = (const float4*)WihP;
  const float4* WH = (const float4*)WhhP;
  for(int task=0;task<TASKS;task++){
    const float* MW = mol_align_w + task*2*FD;
    float mb = mol_align_b[task];
    for(int tt=0;tt<T_STEPS;tt++){
      // score self-dot
      float pv = (t<FD)? MW[t]*ACTM[t] : 0.f;
      float sm = bsum512(pv, red);
      float sc = -1e30f;
      if(t<Lm){
        float am = amask[b*Lm+t];
        sc = lrelu(sm + sact2[(size_t)task*NROWS + b*Lm + t] + mb) + (am==0.f?NEGV:0.f);
      }
      float mx = bmax512(sc, red);
      float e = (t<Lm)? expf(sc-mx) : 0.f;
      float se = bsum512(e, red);
      if(t<Lm) WL[t] = e/se*amask[b*Lm+t];
      __syncthreads();
      if(t<FD){
        float a0=0.f;
        for(int l=0;l<Lm;l++) a0 += WL[l]*act_t[(size_t)(b*Lm+l)*FD+t];
        XS[t]=eluf(a0);
      }
      __syncthreads();
      // GRU: group A (t<256) computes gi for col t from XS; group B computes gh from HS
      float g0=0.f,g1=0.f,g2=0.f;
      if(t<FD){
        const float4* S4=(const float4*)XS;
        for(int kg=0;kg<FD/4;kg++){
          float4 xq = S4[kg];
          g0 += dot4(xq, WI[kg*768 + tg]);
          g1 += dot4(xq, WI[kg*768 + 256 + tg]);
          g2 += dot4(xq, WI[kg*768 + 512 + tg]);
        }
      } else {
        const float4* S4=(const float4*)HS;
        for(int kg=0;kg<FD/4;kg++){
          float4 hq = S4[kg];
          g0 += dot4(hq, WH[kg*768 + tg]);
          g1 += dot4(hq, WH[kg*768 + 256 + tg]);
          g2 += dot4(hq, WH[kg*768 + 512 + tg]);
        }
        GH[tg]=g0; GH[256+tg]=g1; GH[512+tg]=g2;
      }
      __syncthreads();
      if(t<FD){
        float hp = HS[t];
        float r = sigm(g0+bih[t] + GH[t]+bhh[t]);
        float z = sigm(g1+bih[256+t] + GH[256+t]+bhh[256+t]);
        float n = tanhf(g2+bih[512+t] + r*(GH[512+t]+bhh[512+t]));
        float hn = (1.f-z)*n + z*hp;
        HS[t]=hn;
        float am = fmaxf(hn,0.f);
        ACTM[t]=am;
        if(tt==T_STEPS-1) out[((size_t)task*Bm + b)*FD + t]=am;
      }
      __syncthreads();
    }
  }
}

extern "C" void kernel_launch(void* const* d_in, const int* in_sizes, int n_in,
                              void* d_out, int out_size, void* d_ws, size_t ws_size,
                              hipStream_t stream) {
  (void)in_sizes; (void)n_in; (void)out_size; (void)ws_size;
  const float* atom_list   = (const float*)d_in[0];
  const float* bond_list   = (const float*)d_in[1];
  const int*   adeg        = (const int*)d_in[2];
  const int*   bdeg        = (const int*)d_in[3];
  const float* amask       = (const float*)d_in[4];
  const float* atom_fc_w   = (const float*)d_in[5];
  const float* atom_fc_b   = (const float*)d_in[6];
  const float* nfc_w       = (const float*)d_in[7];
  const float* nfc_b       = (const float*)d_in[8];
  const float* align_w     = (const float*)d_in[9];   // [3,1,512]
  const float* align_b     = (const float*)d_in[10];  // [3,1]
  const float* attend_w    = (const float*)d_in[11];  // [3,256,256]
  const float* attend_b    = (const float*)d_in[12];  // [3,256]
  const float* gru_wih     = (const float*)d_in[13];  // [3,768,256]
  const float* gru_whh     = (const float*)d_in[14];
  const float* gru_bih     = (const float*)d_in[15];  // [3,768]
  const float* gru_bhh     = (const float*)d_in[16];
  const float* mgru_wih    = (const float*)d_in[17];  // [768,256]
  const float* mgru_whh    = (const float*)d_in[18];
  const float* mgru_bih    = (const float*)d_in[19];
  const float* mgru_bhh    = (const float*)d_in[20];
  const float* mol_align_w = (const float*)d_in[21];  // [4,1,512]
  const float* mol_align_b = (const float*)d_in[22];  // [4,1]
  const float* mol_att_w   = (const float*)d_in[23];  // [256,256]
  const float* mol_att_b   = (const float*)d_in[24];
  float* out = (float*)d_out;

  float* ws = (float*)d_ws;
  size_t o=0;
  float* wp_att  = ws+o; o += (size_t)3*FD*FD;
  float* wp_wih  = ws+o; o += (size_t)3*3*WPLANE/2;   // 3 radii x 3 bf16 planes (ih)
  float* wp_whh  = ws+o; o += (size_t)3*3*WPLANE/2;   // same (hh)
  float* wp_mwih = ws+o; o += (size_t)FD*768;
  float* wp_mwhh = ws+o; o += (size_t)FD*768;
  float* wp_matt = ws+o; o += (size_t)FD*FD;
  float* AF   = ws+o; o += (size_t)NROWS*FD;          // atom_feature
  float* AP   = ws+o; o += (size_t)NROWS*FD;          // atom_proj -> ctx -> act_t
  float* BP   = ws+o; o += (size_t)Bm*NBONDSm*FD;     // bond_proj -> {H, ACT}
  float* CPRE = ws+o; o += (size_t)NROWS*FD;
  float* WSUM = ws+o; o += NROWS;
  float* SSELF= ws+o; o += NROWS;
  float* SNBR = ws+o; o += NROWS;
  float* SACT2= ws+o; o += (size_t)TASKS*NROWS;
  float* H   = BP;                  // bond_proj dead after attn0
  float* ACT = BP + (size_t)NROWS*FD;
  ushort* wpb_ih = (ushort*)wp_wih;
  ushort* wpb_hh = (ushort*)wp_whh;

  dim3 tb(256);
  k_pack4<<<dim3(256,3), tb, 0, stream>>>(attend_w, wp_att, FD);
  k_pack3<<<dim3(96,3), tb, 0, stream>>>(gru_wih, wpb_ih);
  k_pack3<<<dim3(96,3), tb, 0, stream>>>(gru_whh, wpb_hh);
  k_pack4<<<dim3(768,1), tb, 0, stream>>>(mgru_wih, wp_mwih, 768);
  k_pack4<<<dim3(768,1), tb, 0, stream>>>(mgru_whh, wp_mwhh, 768);
  k_pack4<<<dim3(256,1), tb, 0, stream>>>(mol_att_w, wp_matt, FD);

  k_atomfc<<<NROWS/16, tb, 0, stream>>>(atom_list, atom_fc_w, atom_fc_b, nfc_w, AF, AP);
  k_bondproj<<<Bm*NBONDSm/16, tb, 0, stream>>>(bond_list, nfc_w, nfc_b, BP);

  // radius 0
  k_attn0<<<NROWS/4, tb, 0, stream>>>(AF, AP, BP, adeg, bdeg, align_w, align_b, CPRE, WSUM);
  k_gemm256<<<NROWS/32, tb, 0, stream>>>(CPRE, wp_att, attend_b, WSUM, AP, 2);
  k_gru_mfma<<<NROWS/16, tb, 0, stream>>>(AP, AF, wpb_ih, wpb_hh, gru_wih,
                                          gru_bih, gru_bhh, H, ACT);

  // radius 1..2
  for(int r=1;r<RADIUS;r++){
    k_dots<<<NROWS/4, tb, 0, stream>>>(ACT, align_w + r*2*FD, SSELF, SNBR);
    k_attnr<<<NROWS/4, tb, 0, stream>>>(ACT, SSELF, SNBR, adeg, align_b + r, CPRE, WSUM);
    k_gemm256<<<NROWS/32, tb, 0, stream>>>(CPRE, wp_att + (size_t)r*FD*FD, attend_b + r*FD, WSUM, AP, 2);
    k_gru_mfma<<<NROWS/16, tb, 0, stream>>>(AP, H,
                                            wpb_ih + (size_t)r*3*WPLANE, wpb_hh + (size_t)r*3*WPLANE,
                                            gru_wih + (size_t)r*WPLANE,
                                            gru_bih + r*768, gru_bhh + r*768, H, ACT);
  }

  // molecule phase
  k_gemm256<<<NROWS/32, tb, 0, stream>>>(ACT, wp_matt, mol_att_b, nullptr, AP, 3); // act_t
  k_sact2<<<NROWS/4, tb, 0, stream>>>(ACT, mol_align_w, SACT2);
  k_molphase<<<Bm, dim3(512), 0, stream>>>(ACT, amask, SACT2, mol_align_w, mol_align_b,
                                           AP, wp_mwih, wp_mwhh, mgru_bih, mgru_bhh, out);
}

// Round 4
// 933.267 us; speedup vs baseline: 1.4184x; 1.0632x over previous
//
#include <hip/hip_runtime.h>
#include <math.h>

#define RADIUS 3
#define T_STEPS 2
#define TASKS 4
#define IN_ATOM 39
#define IN_BOND 10
#define FD 256
#define Bm 128
#define Lm 128
#define Dm 6
#define NBONDSm 256
#define NEGV -9e8f
#define NROWS (Bm*Lm)   /* 16384 */
#define WPLANE 196608   /* 768*256 elements per GRU weight plane */
#define APLANE 65536    /* 256*256 elements per attend weight plane */

typedef __attribute__((ext_vector_type(8))) short bf16x8;
typedef __attribute__((ext_vector_type(4))) float f32x4;

#define MFMA(va,vb,vc) __builtin_amdgcn_mfma_f32_16x16x32_bf16((va),(vb),(vc),0,0,0)

__device__ __forceinline__ float lrelu(float x){ return x > 0.f ? x : 0.01f*x; }
__device__ __forceinline__ float eluf(float x){ return x > 0.f ? x : expm1f(x); }
__device__ __forceinline__ float sigm(float x){ return 1.f/(1.f+expf(-x)); }
__device__ __forceinline__ float dot4(float4 a, float4 b){
  return a.x*b.x + a.y*b.y + a.z*b.z + a.w*b.w;
}
__device__ __forceinline__ float4 lrelu4(float4 v){
  return make_float4(lrelu(v.x),lrelu(v.y),lrelu(v.z),lrelu(v.w));
}
__device__ __forceinline__ float wred(float v){
  #pragma unroll
  for(int o=32;o>0;o>>=1) v += __shfl_xor(v,o,64);
  return v;
}
__device__ __forceinline__ float bsum512(float v, float* red){
  #pragma unroll
  for(int o=32;o>0;o>>=1) v += __shfl_xor(v,o,64);
  __syncthreads();
  if((threadIdx.x&63)==0) red[threadIdx.x>>6]=v;
  __syncthreads();
  float s=0.f;
  #pragma unroll
  for(int i=0;i<8;i++) s+=red[i];
  return s;
}
__device__ __forceinline__ float bmax512(float v, float* red){
  #pragma unroll
  for(int o=32;o>0;o>>=1) v = fmaxf(v,__shfl_xor(v,o,64));
  __syncthreads();
  if((threadIdx.x&63)==0) red[threadIdx.x>>6]=v;
  __syncthreads();
  float s=-1e30f;
  #pragma unroll
  for(int i=0;i<8;i++) s=fmaxf(s,red[i]);
  return s;
}

// fp32 -> bf16 round-to-nearest-even
__device__ __forceinline__ ushort f2bf(float x){
  union { float f; unsigned u; } v; v.f = x;
  unsigned u = v.u;
  unsigned r = (u + 0x7fffu + ((u >> 16) & 1u)) >> 16;
  return (ushort)r;
}
__device__ __forceinline__ float b2f(ushort u){ return __uint_as_float(((unsigned)u)<<16); }

// pack W[n][k] (K=256) -> WP[k/4][N][4]: float4 at (kg*N + n) holds W[n][4kg..4kg+3]
__global__ void k_pack4(const float* __restrict__ W, float* __restrict__ WP, int N){
  int mat = blockIdx.y;
  int idx = blockIdx.x*256 + threadIdx.x;
  if(idx < N*256){
    int n = idx >> 8, k = idx & 255;
    WP[(size_t)mat*N*256 + (size_t)(k>>2)*N*4 + n*4 + (k&3)] = W[(size_t)mat*N*256 + idx];
  }
}

// Dekker 3-way bf16 split + MFMA B-fragment pack, R rows x 256 k per matrix.
// Output per matrix: 3 planes (hi,mid,lo), each frag-packed: frag f = nf*8+ks
// (nf=row/16, ks=k/32); within frag lane l, elem j = W[nf*16+(l&15)][ks*32+(l>>4)*8+j].
// grid.x = R/8, grid.y = #matrices.
__global__ __launch_bounds__(256) void k_pack3n(
  const float* __restrict__ W, ushort* __restrict__ WP, int R){
  const int PL = R*256;
  const float* Wm  = W  + (size_t)blockIdx.y*PL;
  ushort*      WPm = WP + (size_t)blockIdx.y*3*PL;
  int id = blockIdx.x*256 + threadIdx.x;
  int f  = id >> 6;
  int l  = id & 63;
  int nf = f >> 3;
  int ks = f & 7;
  int n  = nf*16 + (l & 15);
  int k  = ks*32 + (l >> 4)*8;
  const float* src = Wm + (size_t)n*256 + k;
  size_t d0 = ((size_t)f*64 + l)*8;
  #pragma unroll
  for(int j=0;j<8;j++){
    float x = src[j];
    ushort a = f2bf(x); float r1 = x - b2f(a);
    ushort b = f2bf(r1); float r2 = r1 - b2f(b);
    ushort c = f2bf(r2);
    WPm[d0+j] = a; WPm[PL + d0+j] = b; WPm[2*(size_t)PL + d0+j] = c;
  }
}

// atom_feature = lrelu(atom_list @ atom_fc_w.T + b); atom_proj = atom_list @ nfc_w[:, :39].T
__global__ __launch_bounds__(256) void k_atomfc(
  const float* __restrict__ atom_list, const float* __restrict__ afc_w,
  const float* __restrict__ afc_b, const float* __restrict__ nfc_w,
  float* __restrict__ atom_feature, float* __restrict__ atom_proj){
  __shared__ float Al[16][IN_ATOM];
  int m0 = blockIdx.x*16, t = threadIdx.x;
  for(int i=t;i<16*IN_ATOM;i+=256)
    Al[i/IN_ATOM][i%IN_ATOM] = atom_list[(size_t)(m0 + i/IN_ATOM)*IN_ATOM + i%IN_ATOM];
  __syncthreads();
  float accA[16], accP[16];
  #pragma unroll
  for(int m=0;m<16;m++){accA[m]=0.f;accP[m]=0.f;}
  for(int k=0;k<IN_ATOM;k++){
    float wa = afc_w[t*IN_ATOM+k];
    float wn = nfc_w[t*(IN_ATOM+IN_BOND)+k];
    #pragma unroll
    for(int m=0;m<16;m++){ float a=Al[m][k]; accA[m]+=a*wa; accP[m]+=a*wn; }
  }
  float bb = afc_b[t];
  #pragma unroll
  for(int m=0;m<16;m++){
    atom_feature[(size_t)(m0+m)*FD+t] = lrelu(accA[m]+bb);
    atom_proj[(size_t)(m0+m)*FD+t]    = accP[m];
  }
}

// bond_proj = bond_list @ nfc_w[:, 39:49].T + nfc_b
__global__ __launch_bounds__(256) void k_bondproj(
  const float* __restrict__ bond_list, const float* __restrict__ nfc_w,
  const float* __restrict__ nfc_b, float* __restrict__ bond_proj){
  __shared__ float Bl[16][IN_BOND];
  int m0 = blockIdx.x*16, t=threadIdx.x;
  for(int i=t;i<16*IN_BOND;i+=256)
    Bl[i/IN_BOND][i%IN_BOND] = bond_list[(size_t)(m0+i/IN_BOND)*IN_BOND + i%IN_BOND];
  __syncthreads();
  float acc[16];
  #pragma unroll
  for(int m=0;m<16;m++) acc[m]=0.f;
  for(int k=0;k<IN_BOND;k++){
    float wn = nfc_w[t*(IN_ATOM+IN_BOND)+IN_ATOM+k];
    #pragma unroll
    for(int m=0;m<16;m++) acc[m]+=Bl[m][k]*wn;
  }
  float bb=nfc_b[t];
  #pragma unroll
  for(int m=0;m<16;m++) bond_proj[(size_t)(m0+m)*FD+t]=acc[m]+bb;
}

// radius-0 attention, wave-per-row (4 rows/block). lane owns features lane*4..lane*4+3
__global__ __launch_bounds__(256) void k_attn0(
  const float* __restrict__ AF, const float* __restrict__ APj,
  const float* __restrict__ BP, const int* __restrict__ adeg,
  const int* __restrict__ bdeg, const float* __restrict__ align_w,
  const float* __restrict__ align_b, float* __restrict__ cpre, float* __restrict__ wsum){
  int wid = threadIdx.x>>6, lane = threadIdx.x&63;
  int row = blockIdx.x*4 + wid; int b = row >> 7;
  float4 af = *(const float4*)&AF[(size_t)row*FD + lane*4];
  float4 w1 = *(const float4*)&align_w[lane*4];
  float4 w2 = *(const float4*)&align_w[FD + lane*4];
  float s_self = wred(dot4(af,w1));
  int ia[Dm]; float4 nbr[Dm]; float s_n[Dm];
  #pragma unroll
  for(int d=0;d<Dm;d++){
    ia[d] = adeg[row*Dm+d];
    int ib = bdeg[row*Dm+d];
    float4 ap = *(const float4*)&APj[(size_t)(b*Lm+ia[d])*FD + lane*4];
    float4 bp = *(const float4*)&BP[(size_t)(b*NBONDSm+ib)*FD + lane*4];
    float4 nf = lrelu4(make_float4(ap.x+bp.x,ap.y+bp.y,ap.z+bp.z,ap.w+bp.w));
    nbr[d]=nf;
    s_n[d] = wred(dot4(nf,w2));
  }
  float ab = align_b[0];
  float mx=-1e30f; float sc[Dm];
  #pragma unroll
  for(int d=0;d<Dm;d++){
    sc[d]=lrelu(s_self+s_n[d]+ab) + (ia[d]==Lm-1 ? NEGV : 0.f);
    mx = fmaxf(mx, sc[d]);
  }
  float se=0.f, ex[Dm];
  #pragma unroll
  for(int d=0;d<Dm;d++){ ex[d]=expf(sc[d]-mx); se+=ex[d]; }
  float inv=1.f/se, ws=0.f;
  float4 cp = make_float4(0,0,0,0);
  #pragma unroll
  for(int d=0;d<Dm;d++){
    float wd = ex[d]*inv * (ia[d]==Lm-1?0.f:1.f);
    ws+=wd;
    cp.x+=wd*nbr[d].x; cp.y+=wd*nbr[d].y; cp.z+=wd*nbr[d].z; cp.w+=wd*nbr[d].w;
  }
  *(float4*)&cpre[(size_t)row*FD + lane*4] = cp;
  if(lane==0) wsum[row]=ws;
}

// per-row dots with align_w[r], wave-per-row
__global__ __launch_bounds__(256) void k_dots(
  const float* __restrict__ act, const float* __restrict__ w512,
  float* __restrict__ sself, float* __restrict__ snbr){
  int wid=threadIdx.x>>6, lane=threadIdx.x&63;
  int row=blockIdx.x*4+wid;
  float4 aq = *(const float4*)&act[(size_t)row*FD + lane*4];
  float4 w1 = *(const float4*)&w512[lane*4];
  float4 w2 = *(const float4*)&w512[FD + lane*4];
  float s1 = wred(dot4(aq,w1));
  float s2 = wred(dot4(aq,w2));
  if(lane==0){ sself[row]=s1; snbr[row]=s2; }
}

// radius>=1 attention, wave-per-row
__global__ __launch_bounds__(256) void k_attnr(
  const float* __restrict__ activated, const float* __restrict__ sself,
  const float* __restrict__ snbr, const int* __restrict__ adeg,
  const float* __restrict__ align_b, float* __restrict__ cpre, float* __restrict__ wsum){
  int wid=threadIdx.x>>6, lane=threadIdx.x&63;
  int row=blockIdx.x*4+wid; int b=row>>7;
  float ss = sself[row]; float ab=align_b[0];
  int ia[Dm]; float sc[Dm]; float mx=-1e30f;
  #pragma unroll
  for(int d=0;d<Dm;d++){
    ia[d]=adeg[row*Dm+d];
    sc[d]=lrelu(ss+snbr[b*Lm+ia[d]]+ab)+(ia[d]==Lm-1?NEGV:0.f);
    mx=fmaxf(mx,sc[d]);
  }
  float se=0.f, ex[Dm];
  #pragma unroll
  for(int d=0;d<Dm;d++){ ex[d]=expf(sc[d]-mx); se+=ex[d]; }
  float inv=1.f/se, ws=0.f, wd[Dm];
  #pragma unroll
  for(int d=0;d<Dm;d++){ wd[d]=ex[d]*inv*(ia[d]==Lm-1?0.f:1.f); ws+=wd[d]; }
  float4 cp = make_float4(0,0,0,0);
  #pragma unroll
  for(int d=0;d<Dm;d++){
    float4 av = *(const float4*)&activated[(size_t)(b*Lm+ia[d])*FD + lane*4];
    cp.x+=wd[d]*av.x; cp.y+=wd[d]*av.y; cp.z+=wd[d]*av.z; cp.w+=wd[d]*av.w;
  }
  *(float4*)&cpre[(size_t)row*FD + lane*4] = cp;
  if(lane==0) wsum[row]=ws;
}

// bf16x3 MFMA GEMM: C[M,256] = epi( A[M,256] @ W.T ), W pre-split (3 planes, frag-packed).
// 32 rows/block, 8 waves; wave owns 32 cols (2 colfrags), 2 M-frags.
// epi: 2 = elu(acc + wsum[row]*bias), 3 = acc + bias.
// C/D layout (confirmed r1-r3): D[row=(lane>>4)*4+reg][col=lane&15].
__global__ __launch_bounds__(512) void k_gemm_mfma(
  const float* __restrict__ A, const ushort* __restrict__ W3,
  const float* __restrict__ bias, const float* __restrict__ wsum,
  float* __restrict__ C, int epi){
  int lane = threadIdx.x & 63;
  int wv   = threadIdx.x >> 6;
  int rl = lane & 15, rg = lane >> 4;
  int mrow0 = blockIdx.x*32;
  f32x4 acc[2][2];
  f32x4 zero = {0.f,0.f,0.f,0.f};
  #pragma unroll
  for(int c=0;c<2;c++){ acc[c][0]=zero; acc[c][1]=zero; }
  const bf16x8* BW = (const bf16x8*)W3;
  const int PS = APLANE/8;   // 8192

  for(int ks=0;ks<8;ks++){
    bf16x8 x0[2],x1[2],x2[2];
    #pragma unroll
    for(int m=0;m<2;m++){
      const float* xp = A + (size_t)(mrow0 + m*16 + rl)*FD + ks*32 + rg*8;
      #pragma unroll
      for(int j=0;j<8;j++){
        float v = xp[j];
        ushort a = f2bf(v); float r1 = v - b2f(a);
        ushort b = f2bf(r1); float r2 = r1 - b2f(b);
        x0[m][j]=(short)a; x1[m][j]=(short)b; x2[m][j]=(short)f2bf(r2);
      }
    }
    #pragma unroll
    for(int c=0;c<2;c++){
      size_t fb = ((size_t)((wv*2+c)*8 + ks))*64 + lane;
      bf16x8 b0 = BW[fb], b1 = BW[fb+PS], b2 = BW[fb+2*PS];
      #pragma unroll
      for(int m=0;m<2;m++){
        f32x4 a = acc[c][m];
        a = MFMA(x0[m],b0,a); a = MFMA(x1[m],b0,a); a = MFMA(x0[m],b1,a);
        a = MFMA(x2[m],b0,a); a = MFMA(x1[m],b1,a); a = MFMA(x0[m],b2,a);
        acc[c][m]=a;
      }
    }
  }
  #pragma unroll
  for(int c=0;c<2;c++){
    int col = (wv*2+c)*16 + rl;
    float bb = bias[col];
    #pragma unroll
    for(int m=0;m<2;m++){
      #pragma unroll
      for(int i=0;i<4;i++){
        int row = mrow0 + m*16 + rg*4 + i;
        float v = acc[c][m][i];
        if(epi==2){ v = eluf(v + wsum[row]*bb); }
        else      { v += bb; }
        C[(size_t)row*FD+col] = v;
      }
    }
  }
}

// bf16x3 MFMA GRU (~fp32 precision). 32 rows/block, 8 waves, 512 threads;
// wave owns 32 within-gate cols (2 colfrags) across all 6 gate matrices.
// I-phase and H-phase loop-split so A-split registers are reused.
// In-place H update: __syncthreads() after K-loop (all Hprev reads) before writes.
__global__ __launch_bounds__(512) void k_gru_mfma(
  const float* __restrict__ X, const float* Hprev,
  const ushort* __restrict__ WI3, const ushort* __restrict__ WH3,
  const float* __restrict__ bih, const float* __restrict__ bhh,
  float* Hout, float* __restrict__ Act){
  int lane = threadIdx.x & 63;
  int wv   = threadIdx.x >> 6;       // 0..7
  int rl = lane & 15, rg = lane >> 4;
  int mrow0 = blockIdx.x*32;

  f32x4 accI[3][2][2], accH[3][2][2];
  f32x4 zero = {0.f,0.f,0.f,0.f};
  #pragma unroll
  for(int g=0;g<3;g++)
    #pragma unroll
    for(int c=0;c<2;c++){
      accI[g][c][0]=zero; accI[g][c][1]=zero;
      accH[g][c][0]=zero; accH[g][c][1]=zero;
    }

  const bf16x8* BI = (const bf16x8*)WI3;
  const bf16x8* BH = (const bf16x8*)WH3;
  const int PS = WPLANE/8;           // 24576

  for(int ks=0;ks<8;ks++){
    // ---- I-phase: split X, accumulate gi ----
    {
      bf16x8 x0[2],x1[2],x2[2];
      #pragma unroll
      for(int m=0;m<2;m++){
        const float* xp = X + (size_t)(mrow0 + m*16 + rl)*FD + ks*32 + rg*8;
        #pragma unroll
        for(int j=0;j<8;j++){
          float v = xp[j];
          ushort a = f2bf(v); float r1 = v - b2f(a);
          ushort b = f2bf(r1); float r2 = r1 - b2f(b);
          x0[m][j]=(short)a; x1[m][j]=(short)b; x2[m][j]=(short)f2bf(r2);
        }
      }
      #pragma unroll
      for(int c=0;c<2;c++){
        #pragma unroll
        for(int g=0;g<3;g++){
          size_t fb = ((size_t)((g*16 + wv*2 + c)*8 + ks))*64 + lane;
          bf16x8 b0 = BI[fb], b1 = BI[fb+PS], b2 = BI[fb+2*PS];
          #pragma unroll
          for(int m=0;m<2;m++){
            f32x4 a = accI[g][c][m];
            a = MFMA(x0[m],b0,a); a = MFMA(x1[m],b0,a); a = MFMA(x0[m],b1,a);
            a = MFMA(x2[m],b0,a); a = MFMA(x1[m],b1,a); a = MFMA(x0[m],b2,a);
            accI[g][c][m]=a;
          }
        }
      }
    }
    // ---- H-phase: split Hprev, accumulate gh ----
    {
      bf16x8 h0[2],h1[2],h2[2];
      #pragma unroll
      for(int m=0;m<2;m++){
        const float* hq = Hprev + (size_t)(mrow0 + m*16 + rl)*FD + ks*32 + rg*8;
        #pragma unroll
        for(int j=0;j<8;j++){
          float w = hq[j];
          ushort d = f2bf(w); float s1 = w - b2f(d);
          ushort e = f2bf(s1); float s2 = s1 - b2f(e);
          h0[m][j]=(short)d; h1[m][j]=(short)e; h2[m][j]=(short)f2bf(s2);
        }
      }
      #pragma unroll
      for(int c=0;c<2;c++){
        #pragma unroll
        for(int g=0;g<3;g++){
          size_t fb = ((size_t)((g*16 + wv*2 + c)*8 + ks))*64 + lane;
          bf16x8 b0 = BH[fb], b1 = BH[fb+PS], b2 = BH[fb+2*PS];
          #pragma unroll
          for(int m=0;m<2;m++){
            f32x4 a = accH[g][c][m];
            a = MFMA(h0[m],b0,a); a = MFMA(h1[m],b0,a); a = MFMA(h0[m],b1,a);
            a = MFMA(h2[m],b0,a); a = MFMA(h1[m],b1,a); a = MFMA(h0[m],b2,a);
            accH[g][c][m]=a;
          }
        }
      }
    }
  }
  __syncthreads();   // all Hprev reads complete before any in-place Hout write

  #pragma unroll
  for(int c=0;c<2;c++){
    int col = (wv*2+c)*16 + rl;
    float br=bih[col],   bz=bih[FD+col],   bn=bih[2*FD+col];
    float cr=bhh[col],   cz=bhh[FD+col],   cn=bhh[2*FD+col];
    #pragma unroll
    for(int m=0;m<2;m++){
      #pragma unroll
      for(int i=0;i<4;i++){
        int row = mrow0 + m*16 + rg*4 + i;
        float hp = Hprev[(size_t)row*FD + col];
        float r = sigm(accI[0][c][m][i] + br + accH[0][c][m][i] + cr);
        float z = sigm(accI[1][c][m][i] + bz + accH[1][c][m][i] + cz);
        float n = tanhf(accI[2][c][m][i] + bn + r*(accH[2][c][m][i] + cn));
        float hn = (1.f-z)*n + z*hp;
        Hout[(size_t)row*FD+col] = hn;
        Act[(size_t)row*FD+col]  = fmaxf(hn, 0.f);
      }
    }
  }
}

// per-task dots of activated with mol_align_w[i][0][256:512], wave-per-row
__global__ __launch_bounds__(256) void k_sact2(
  const float* __restrict__ act, const float* __restrict__ mol_align_w,
  float* __restrict__ sact2){
  int wid=threadIdx.x>>6, lane=threadIdx.x&63;
  int row=blockIdx.x*4+wid;
  float4 aq = *(const float4*)&act[(size_t)row*FD + lane*4];
  #pragma unroll
  for(int i=0;i<TASKS;i++){
    float4 wq = *(const float4*)&mol_align_w[i*2*FD + FD + lane*4];
    float s = wred(dot4(aq,wq));
    if(lane==0) sact2[(size_t)i*NROWS+row]=s;
  }
}

// fused mol phase: one block per molecule, 512 threads, all TASKS x T_STEPS inside.
__global__ __launch_bounds__(512) void k_molphase(
  const float* __restrict__ ACT, const float* __restrict__ amask,
  const float* __restrict__ sact2, const float* __restrict__ mol_align_w,
  const float* __restrict__ mol_align_b, const float* __restrict__ act_t,
  const float* __restrict__ WihP, const float* __restrict__ WhhP,
  const float* __restrict__ bih, const float* __restrict__ bhh,
  float* __restrict__ out){
  __shared__ __align__(16) float HS[FD];
  __shared__ __align__(16) float XS[FD];
  __shared__ float ACTM[FD];
  __shared__ float GH[3*FD];
  __shared__ float WL[Lm];
  __shared__ float red[8];
  int b = blockIdx.x;
  int t = threadIdx.x;        // 0..511
  int tg = t & 255;
  // mol_feature = sum_l ACT*mask
  if(t<FD){
    float s=0.f;
    for(int l=0;l<Lm;l++) s += ACT[(size_t)(b*Lm+l)*FD+t]*amask[b*Lm+l];
    HS[t]=s; ACTM[t]=fmaxf(s,0.f);
  }
  __syncthreads();
  const float4* WI = (const float4*)WihP;
  const float4* WH = (const float4*)WhhP;
  for(int task=0;task<TASKS;task++){
    const float* MW = mol_align_w + task*2*FD;
    float mb = mol_align_b[task];
    for(int tt=0;tt<T_STEPS;tt++){
      // score self-dot
      float pv = (t<FD)? MW[t]*ACTM[t] : 0.f;
      float sm = bsum512(pv, red);
      float sc = -1e30f;
      if(t<Lm){
        float am = amask[b*Lm+t];
        sc = lrelu(sm + sact2[(size_t)task*NROWS + b*Lm + t] + mb) + (am==0.f?NEGV:0.f);
      }
      float mx = bmax512(sc, red);
      float e = (t<Lm)? expf(sc-mx) : 0.f;
      float se = bsum512(e, red);
      if(t<Lm) WL[t] = e/se*amask[b*Lm+t];
      __syncthreads();
      if(t<FD){
        float a0=0.f;
        for(int l=0;l<Lm;l++) a0 += WL[l]*act_t[(size_t)(b*Lm+l)*FD+t];
        XS[t]=eluf(a0);
      }
      __syncthreads();
      // GRU: group A (t<256) computes gi for col t from XS; group B computes gh from HS
      float g0=0.f,g1=0.f,g2=0.f;
      if(t<FD){
        const float4* S4=(const float4*)XS;
        for(int kg=0;kg<FD/4;kg++){
          float4 xq = S4[kg];
          g0 += dot4(xq, WI[kg*768 + tg]);
          g1 += dot4(xq, WI[kg*768 + 256 + tg]);
          g2 += dot4(xq, WI[kg*768 + 512 + tg]);
        }
      } else {
        const float4* S4=(const float4*)HS;
        for(int kg=0;kg<FD/4;kg++){
          float4 hq = S4[kg];
          g0 += dot4(hq, WH[kg*768 + tg]);
          g1 += dot4(hq, WH[kg*768 + 256 + tg]);
          g2 += dot4(hq, WH[kg*768 + 512 + tg]);
        }
        GH[tg]=g0; GH[256+tg]=g1; GH[512+tg]=g2;
      }
      __syncthreads();
      if(t<FD){
        float hp = HS[t];
        float r = sigm(g0+bih[t] + GH[t]+bhh[t]);
        float z = sigm(g1+bih[256+t] + GH[256+t]+bhh[256+t]);
        float n = tanhf(g2+bih[512+t] + r*(GH[512+t]+bhh[512+t]));
        float hn = (1.f-z)*n + z*hp;
        HS[t]=hn;
        float am = fmaxf(hn,0.f);
        ACTM[t]=am;
        if(tt==T_STEPS-1) out[((size_t)task*Bm + b)*FD + t]=am;
      }
      __syncthreads();
    }
  }
}

extern "C" void kernel_launch(void* const* d_in, const int* in_sizes, int n_in,
                              void* d_out, int out_size, void* d_ws, size_t ws_size,
                              hipStream_t stream) {
  (void)in_sizes; (void)n_in; (void)out_size; (void)ws_size;
  const float* atom_list   = (const float*)d_in[0];
  const float* bond_list   = (const float*)d_in[1];
  const int*   adeg        = (const int*)d_in[2];
  const int*   bdeg        = (const int*)d_in[3];
  const float* amask       = (const float*)d_in[4];
  const float* atom_fc_w   = (const float*)d_in[5];
  const float* atom_fc_b   = (const float*)d_in[6];
  const float* nfc_w       = (const float*)d_in[7];
  const float* nfc_b       = (const float*)d_in[8];
  const float* align_w     = (const float*)d_in[9];   // [3,1,512]
  const float* align_b     = (const float*)d_in[10];  // [3,1]
  const float* attend_w    = (const float*)d_in[11];  // [3,256,256]
  const float* attend_b    = (const float*)d_in[12];  // [3,256]
  const float* gru_wih     = (const float*)d_in[13];  // [3,768,256]
  const float* gru_whh     = (const float*)d_in[14];
  const float* gru_bih     = (const float*)d_in[15];  // [3,768]
  const float* gru_bhh     = (const float*)d_in[16];
  const float* mgru_wih    = (const float*)d_in[17];  // [768,256]
  const float* mgru_whh    = (const float*)d_in[18];
  const float* mgru_bih    = (const float*)d_in[19];
  const float* mgru_bhh    = (const float*)d_in[20];
  const float* mol_align_w = (const float*)d_in[21];  // [4,1,512]
  const float* mol_align_b = (const float*)d_in[22];  // [4,1]
  const float* mol_att_w   = (const float*)d_in[23];  // [256,256]
  const float* mol_att_b   = (const float*)d_in[24];
  float* out = (float*)d_out;

  float* ws = (float*)d_ws;
  size_t o=0;
  float* wp_att  = ws+o; o += (size_t)3*3*APLANE/2;   // attend bf16x3 (3 radii)
  float* wp_wih  = ws+o; o += (size_t)3*3*WPLANE/2;   // GRU Wih bf16x3 (3 radii)
  float* wp_whh  = ws+o; o += (size_t)3*3*WPLANE/2;   // GRU Whh bf16x3
  float* wp_mwih = ws+o; o += (size_t)FD*768;         // mol GRU fp32 pack4
  float* wp_mwhh = ws+o; o += (size_t)FD*768;
  float* wp_matt = ws+o; o += (size_t)3*APLANE/2;     // mol_att bf16x3
  float* AF   = ws+o; o += (size_t)NROWS*FD;          // atom_feature
  float* AP   = ws+o; o += (size_t)NROWS*FD;          // atom_proj -> ctx -> act_t
  float* BP   = ws+o; o += (size_t)Bm*NBONDSm*FD;     // bond_proj -> {H, ACT}
  float* CPRE = ws+o; o += (size_t)NROWS*FD;
  float* WSUM = ws+o; o += NROWS;
  float* SSELF= ws+o; o += NROWS;
  float* SNBR = ws+o; o += NROWS;
  float* SACT2= ws+o; o += (size_t)TASKS*NROWS;
  float* H   = BP;                  // bond_proj dead after attn0
  float* ACT = BP + (size_t)NROWS*FD;
  ushort* wpb_att = (ushort*)wp_att;
  ushort* wpb_ih  = (ushort*)wp_wih;
  ushort* wpb_hh  = (ushort*)wp_whh;
  ushort* wpb_matt= (ushort*)wp_matt;

  dim3 tb(256);
  k_pack3n<<<dim3(32,3), tb, 0, stream>>>(attend_w, wpb_att, 256);
  k_pack3n<<<dim3(96,3), tb, 0, stream>>>(gru_wih, wpb_ih, 768);
  k_pack3n<<<dim3(96,3), tb, 0, stream>>>(gru_whh, wpb_hh, 768);
  k_pack3n<<<dim3(32,1), tb, 0, stream>>>(mol_att_w, wpb_matt, 256);
  k_pack4<<<dim3(768,1), tb, 0, stream>>>(mgru_wih, wp_mwih, 768);
  k_pack4<<<dim3(768,1), tb, 0, stream>>>(mgru_whh, wp_mwhh, 768);

  k_atomfc<<<NROWS/16, tb, 0, stream>>>(atom_list, atom_fc_w, atom_fc_b, nfc_w, AF, AP);
  k_bondproj<<<Bm*NBONDSm/16, tb, 0, stream>>>(bond_list, nfc_w, nfc_b, BP);

  // radius 0
  k_attn0<<<NROWS/4, tb, 0, stream>>>(AF, AP, BP, adeg, bdeg, align_w, align_b, CPRE, WSUM);
  k_gemm_mfma<<<NROWS/32, dim3(512), 0, stream>>>(CPRE, wpb_att, attend_b, WSUM, AP, 2);
  k_gru_mfma<<<NROWS/32, dim3(512), 0, stream>>>(AP, AF, wpb_ih, wpb_hh,
                                                 gru_bih, gru_bhh, H, ACT);

  // radius 1..2
  for(int r=1;r<RADIUS;r++){
    k_dots<<<NROWS/4, tb, 0, stream>>>(ACT, align_w + r*2*FD, SSELF, SNBR);
    k_attnr<<<NROWS/4, tb, 0, stream>>>(ACT, SSELF, SNBR, adeg, align_b + r, CPRE, WSUM);
    k_gemm_mfma<<<NROWS/32, dim3(512), 0, stream>>>(CPRE, wpb_att + (size_t)r*3*APLANE,
                                                    attend_b + r*FD, WSUM, AP, 2);
    k_gru_mfma<<<NROWS/32, dim3(512), 0, stream>>>(AP, H,
                                                   wpb_ih + (size_t)r*3*WPLANE,
                                                   wpb_hh + (size_t)r*3*WPLANE,
                                                   gru_bih + r*768, gru_bhh + r*768, H, ACT);
  }

  // molecule phase
  k_gemm_mfma<<<NROWS/32, dim3(512), 0, stream>>>(ACT, wpb_matt, mol_att_b, nullptr, AP, 3);
  k_sact2<<<NROWS/4, tb, 0, stream>>>(ACT, mol_align_w, SACT2);
  k_molphase<<<Bm, dim3(512), 0, stream>>>(ACT, amask, SACT2, mol_align_w, mol_align_b,
                                           AP, wp_mwih, wp_mwhh, mgru_bih, mgru_bhh, out);
}